// Round 5
// baseline (460.796 us; speedup 1.0000x reference)
//
#include <hip/hip_runtime.h>

// Green-anchor kernel. Root cause of R1-R4 aborts: setup_inputs() interleaves
// keys (rgb0, depth0, rgb1, depth1, ...) — d_in mapping fixed accordingly.
// Dtypes are fp32 (in/out npz sizes match fp32, reference is float32).
//
// d_out = concat(corr3, corr2, corr1, corr0)  (reference return order)
// corr[bb, pi, pj, i, j] = sum_c a[bb,c,i,j] * bpad[bb,c, i+pi-4, j+pj-4]
//
// Thread = (bb, pi, i, j); register-reuse of a-load across the 9 pj values.

__global__ void __launch_bounds__(256)
corr_pj_kernel(const float* __restrict__ a, const float* __restrict__ b,
               float* __restrict__ out, int C, int H, int W, int nth)
{
    int idx = blockIdx.x * blockDim.x + threadIdx.x;
    if (idx >= nth) return;

    int j  = idx % W;
    int t  = idx / W;
    int i  = t % H;  t /= H;
    int pi = t % 9;  t /= 9;
    int bb = t;

    const int r  = i + pi - 4;
    const int hw = H * W;

    float acc[9];
    #pragma unroll
    for (int pj = 0; pj < 9; ++pj) acc[pj] = 0.f;

    if ((unsigned)r < (unsigned)H) {
        const float* __restrict__ ap = a + ((size_t)(bb * C) * H + i) * W + j;
        const float* __restrict__ bp = b + ((size_t)(bb * C) * H + r) * W; // row base
        for (int c = 0; c < C; ++c) {
            const float av = ap[0];
            #pragma unroll
            for (int pj = 0; pj < 9; ++pj) {
                const int jj = j + pj - 4;
                const float bv = ((unsigned)jj < (unsigned)W) ? bp[jj] : 0.f;
                acc[pj] = fmaf(av, bv, acc[pj]);
            }
            ap += hw;
            bp += hw;
        }
    }

    #pragma unroll
    for (int pj = 0; pj < 9; ++pj) {
        out[(((size_t)(bb * 9 + pi) * 9 + pj) * H + i) * W + j] = acc[pj];
    }
}

extern "C" void kernel_launch(void* const* d_in, const int* in_sizes, int n_in,
                              void* d_out, int out_size, void* d_ws, size_t ws_size,
                              hipStream_t stream) {
    // setup_inputs() dict order: rgb0, depth0, rgb1, depth1, rgb2, depth2, rgb3, depth3
    const float* a0 = (const float*)d_in[0];  // rgb0   [8,64,112,112]
    const float* b0 = (const float*)d_in[1];  // depth0 [8,64,112,112]
    const float* a1 = (const float*)d_in[2];  // rgb1   [8,128,56,56]
    const float* b1 = (const float*)d_in[3];  // depth1 [8,128,56,56]
    const float* a2 = (const float*)d_in[4];  // rgb2   [8,256,28,28]
    const float* b2 = (const float*)d_in[5];  // depth2 [8,256,28,28]
    const float* a3 = (const float*)d_in[6];  // rgb3   [8,512,14,14]
    const float* b3 = (const float*)d_in[7];  // depth3 [8,512,14,14]
    float* out = (float*)d_out;

    // Region sizes (elements), d_out = corr3 | corr2 | corr1 | corr0
    const int n3 = 8 * 81 * 14 * 14;      // 127008
    const int n2 = 8 * 81 * 28 * 28;      // 508032
    const int n1 = 8 * 81 * 56 * 56;      // 2032128
    float* o3 = out;
    float* o2 = o3 + n3;
    float* o1 = o2 + n2;
    float* o0 = o1 + n1;

    // threads = 8 * 9 * H * W per level
    const int t3 = 8 * 9 * 14 * 14;       // 14112
    const int t2 = 8 * 9 * 28 * 28;       // 56448
    const int t1 = 8 * 9 * 56 * 56;       // 225792
    const int t0 = 8 * 9 * 112 * 112;     // 903168

    hipLaunchKernelGGL(corr_pj_kernel, dim3((t3 + 255) / 256), dim3(256), 0, stream,
                       a3, b3, o3, 512, 14, 14, t3);
    hipLaunchKernelGGL(corr_pj_kernel, dim3((t2 + 255) / 256), dim3(256), 0, stream,
                       a2, b2, o2, 256, 28, 28, t2);
    hipLaunchKernelGGL(corr_pj_kernel, dim3((t1 + 255) / 256), dim3(256), 0, stream,
                       a1, b1, o1, 128, 56, 56, t1);
    hipLaunchKernelGGL(corr_pj_kernel, dim3((t0 + 255) / 256), dim3(256), 0, stream,
                       a0, b0, o0, 64, 112, 112, t0);
}